// Round 6
// baseline (5865.825 us; speedup 1.0000x reference)
//
#include <hip/hip_runtime.h>
#include <stdint.h>

// GRU S=512, B=64, D=H=1024, L=2 — persistent cooperative pipeline, v7 (resubmit).
// Round-5 bench died with "container failed twice" (no compile error, no
// wrong-answer, no profile); deadlock/resource audit found no kernel fault and
// rounds 3-4 infra timing was already degraded -> infra flake. Resubmitting.
//
// Theory: period = broadcast-read BW at the LLC (~3 TB/s observed); traffic
// scales with #reader-WGs. v7 halves readers: tasks 1,2,3 use 32 WGs x 32
// output cols (was 64 x 16). 160 WGs total:
//   blocks   0..63 : task0  xlin0[t] = x[t] @ wih0^T + bih0   (unchanged, 64 slices)
//   blocks  64..95 : task1  layer-0 GRU step t                (32 WGs, 32 cols)
//   blocks  96..127: task2  xlin1[t] = out0[t] @ wih1^T + bih1 (32 WGs, 32 cols)
//   blocks 128..159: task3  layer-1 GRU step t -> d_out       (32 WGs, 32 cols)
// Weight residency at 32 cols = 192 KB > 160 KB LDS, so: r,z gates (128 KB)
// LDS-persistent; n-gate streamed from L2 (clean weights -> normal cached
// loads, 4-deep register prefetch). o0r eliminated: task2 reads h0b via a
// 4-deep h-ring. Sync = v3 mechanics (store-only per-WG flags, wave-0
// parallel poll, tail barrier + tid0 flag).

#define SLEN 512
#define HB   65536
#define G3   3072
#define XLSLOT (64 * 64 * 48)   // floats per xlin ring slot: [slice16][row64][gate3][col16]

typedef __attribute__((ext_vector_type(8))) short bf16x8;
typedef __attribute__((ext_vector_type(4))) float f32x4;
typedef __attribute__((ext_vector_type(8))) uint16_t u16x8;

__device__ __forceinline__ uint16_t f32_to_bf16(float f) {
  uint32_t u = __float_as_uint(f);
  uint32_t r = u + 0x7FFFu + ((u >> 16) & 1u);
  return (uint16_t)(r >> 16);
}
__device__ __forceinline__ float sigmoid_fast(float x) { return 1.0f / (1.0f + __expf(-x)); }
__device__ __forceinline__ float tanh_fast(float x) { return 1.0f - 2.0f / (1.0f + __expf(2.0f * x)); }
__device__ __forceinline__ void async_cp16(const void* g, void* l) {
  __builtin_amdgcn_global_load_lds((const __attribute__((address_space(1))) void*)g,
                                   (__attribute__((address_space(3))) void*)l, 16, 0, 0);
}
__device__ __forceinline__ void st_u16_llc(uint16_t* p, uint16_t v) {
  __hip_atomic_store(p, v, __ATOMIC_RELAXED, __HIP_MEMORY_SCOPE_AGENT);
}
__device__ __forceinline__ void st_f32_llc(float* p, float v) {
  __hip_atomic_store(p, v, __ATOMIC_RELAXED, __HIP_MEMORY_SCOPE_AGENT);
}
__device__ __forceinline__ float ld_f32_llc(const float* p) {
  return __hip_atomic_load(p, __ATOMIC_RELAXED, __HIP_MEMORY_SCOPE_AGENT);
}
__device__ __forceinline__ void drain_vmem() {
  asm volatile("s_waitcnt vmcnt(0)" ::: "memory");
}
__device__ __forceinline__ int ld_flag(const int* p) {
  return __hip_atomic_load(p, __ATOMIC_RELAXED, __HIP_MEMORY_SCOPE_AGENT);
}
__device__ __forceinline__ void st_flag(int* p, int v) {
  __hip_atomic_store(p, v, __ATOMIC_RELAXED, __HIP_MEMORY_SCOPE_AGENT);
}

// ---- prep kernels -----------------------------------------------------------

__global__ __launch_bounds__(256) void convert_x(const float* __restrict__ src,
                                                 uint16_t* __restrict__ dst) {
  size_t i = ((size_t)blockIdx.x * 256 + threadIdx.x) * 8;
  const float4* s = (const float4*)(src + i);
  float4 a = s[0], b = s[1];
  u16x8 v;
  v[0] = f32_to_bf16(a.x); v[1] = f32_to_bf16(a.y);
  v[2] = f32_to_bf16(a.z); v[3] = f32_to_bf16(a.w);
  v[4] = f32_to_bf16(b.x); v[5] = f32_to_bf16(b.y);
  v[6] = f32_to_bf16(b.z); v[7] = f32_to_bf16(b.w);
  *(u16x8*)(dst + i) = v;
}

// (3072x1024 f32, row-major) -> MFMA B-fragment order:
// chunk = (tile*32 + ks)*64 + lane, holding w[16*tile + (lane&15)][32ks + (lane>>4)*8 ..+7]
__global__ __launch_bounds__(256) void pack_w(const float* __restrict__ src,
                                              uint16_t* __restrict__ dst) {
  int tid = blockIdx.x * 256 + threadIdx.x;
  int tile = tid >> 11, rem = tid & 2047, ks = rem >> 6, lane = rem & 63;
  int row = tile * 16 + (lane & 15);
  int k0 = ks * 32 + (lane >> 4) * 8;
  const float* s = src + (size_t)row * 1024 + k0;
  u16x8 v;
#pragma unroll
  for (int j = 0; j < 8; ++j) v[j] = f32_to_bf16(s[j]);
  *(u16x8*)(dst + (size_t)tid * 8) = v;
}

__global__ __launch_bounds__(256) void init_state(const float* __restrict__ hx,
                                                  uint16_t* __restrict__ h0b,
                                                  uint16_t* __restrict__ h1b,
                                                  int* __restrict__ flags) {
  int i = blockIdx.x * 256 + threadIdx.x;   // 65536 threads
  h0b[i] = f32_to_bf16(hx[i]);              // h0 ring slot 0
  h1b[i] = f32_to_bf16(hx[HB + i]);         // h1 ring slot 0
  if (blockIdx.x < 16) flags[blockIdx.x * 256 + threadIdx.x] = 0;  // 4096 ints
}

// ---- parallel flag wait (wave 0 only) --------------------------------------
// Up to 3 per-lane conditions: *aK >= tK, disabled if tK <= 0. Monotonic.
__device__ __forceinline__ void pollA(const int* a0, int t0,
                                      const int* a1, int t1,
                                      const int* a2, int t2) {
  const int BIG = 0x7fffffff;
  int v0 = (t0 > 0) ? ld_flag(a0) : BIG;
  int v1 = (t1 > 0) ? ld_flag(a1) : BIG;
  int v2 = (t2 > 0) ? ld_flag(a2) : BIG;
  int it = 0;
  while (!__all((v0 >= t0) & (v1 >= t1) & (v2 >= t2))) {
    __builtin_amdgcn_s_sleep(1);
    if (v0 < t0) v0 = ld_flag(a0);
    if (v1 < t1) v1 = ld_flag(a1);
    if (v2 < t2) v2 = ld_flag(a2);
    if (++it > (1 << 22)) break;   // safety valve vs hang
  }
}

// ---- device-scope (sc1) A-load batch ---------------------------------------
// 16 A-fragments, waits vmcnt(0) inside.
__device__ __forceinline__ void load_a16_sc1(const uint16_t* p, bf16x8* a) {
  asm volatile(
      "global_load_dwordx4 %0, %16, off sc1\n\t"
      "global_load_dwordx4 %1, %16, off offset:64 sc1\n\t"
      "global_load_dwordx4 %2, %16, off offset:128 sc1\n\t"
      "global_load_dwordx4 %3, %16, off offset:192 sc1\n\t"
      "global_load_dwordx4 %4, %16, off offset:256 sc1\n\t"
      "global_load_dwordx4 %5, %16, off offset:320 sc1\n\t"
      "global_load_dwordx4 %6, %16, off offset:384 sc1\n\t"
      "global_load_dwordx4 %7, %16, off offset:448 sc1\n\t"
      "global_load_dwordx4 %8, %16, off offset:512 sc1\n\t"
      "global_load_dwordx4 %9, %16, off offset:576 sc1\n\t"
      "global_load_dwordx4 %10, %16, off offset:640 sc1\n\t"
      "global_load_dwordx4 %11, %16, off offset:704 sc1\n\t"
      "global_load_dwordx4 %12, %16, off offset:768 sc1\n\t"
      "global_load_dwordx4 %13, %16, off offset:832 sc1\n\t"
      "global_load_dwordx4 %14, %16, off offset:896 sc1\n\t"
      "global_load_dwordx4 %15, %16, off offset:960 sc1\n\t"
      "s_waitcnt vmcnt(0)"
      : "=&v"(a[0]), "=&v"(a[1]), "=&v"(a[2]), "=&v"(a[3]),
        "=&v"(a[4]), "=&v"(a[5]), "=&v"(a[6]), "=&v"(a[7]),
        "=&v"(a[8]), "=&v"(a[9]), "=&v"(a[10]), "=&v"(a[11]),
        "=&v"(a[12]), "=&v"(a[13]), "=&v"(a[14]), "=&v"(a[15])
      : "v"(p)
      : "memory");
}

// ---- persistent kernel ------------------------------------------------------

#define MFMA_BF16 __builtin_amdgcn_mfma_f32_16x16x32_bf16

// task0 helper: B frags with gate stride 16384 u16.
__device__ __forceinline__ void mfma16(const bf16x8* av, const uint16_t* bbase, int lane,
                                       f32x4& acc0, f32x4& acc1, f32x4& acc2) {
#pragma unroll
  for (int ks = 0; ks < 16; ++ks) {
    const uint16_t* bp = bbase + (size_t)(ks * 64 + lane) * 8;
    bf16x8 b0 = *(const bf16x8*)(bp);
    bf16x8 b1 = *(const bf16x8*)(bp + 16384);
    bf16x8 b2 = *(const bf16x8*)(bp + 32768);
    acc0 = MFMA_BF16(av[ks], b0, acc0, 0, 0, 0);
    acc1 = MFMA_BF16(av[ks], b1, acc1, 0, 0, 0);
    acc2 = MFMA_BF16(av[ks], b2, acc2, 0, 0, 0);
  }
}

__global__ __launch_bounds__(256, 1) void gru_persist(
    const uint16_t* __restrict__ x_bf,
    const uint16_t* __restrict__ wih0, const uint16_t* __restrict__ whh0,
    const uint16_t* __restrict__ wih1, const uint16_t* __restrict__ whh1,
    const float* __restrict__ bih0, const float* __restrict__ bhh0,
    const float* __restrict__ bih1, const float* __restrict__ bhh1,
    const float* __restrict__ hx,
    float* __restrict__ xl0, float* __restrict__ xl1,
    uint16_t* __restrict__ h0b, uint16_t* __restrict__ h1b,
    int* __restrict__ flags,
    float* __restrict__ out) {
  // 128 KB LDS. task0: 96 KB (full 16-col slice). tasks123: r,z 32-col slices.
  __shared__ uint16_t blds[65536];

  const int b = blockIdx.x;
  const int task = (b < 64) ? 0 : 1 + ((b - 64) >> 5);
  const int slice = b & 63;                 // task0 only
  const int w = (b - 64) & 31;              // tasks 1,2,3
  const int tid = threadIdx.x;
  const int lane = tid & 63;
  const int wv = tid >> 6;
  const int r15 = lane & 15;
  const int q = lane >> 4;
  const int m = 16 * wv + 4 * q;            // batch row base

  // store-only flags, one 64B line per producer WG
  int* done0 = flags;                       // 64 entries (task0 slices)
  int* done1 = flags + 1024;                // 32 entries
  int* done2 = flags + 2048;                // 32 entries
  int* done3 = flags + 3072;                // 32 entries

  const uint16_t* Bw = (task == 0) ? wih0 : (task == 1) ? whh0 : (task == 2) ? wih1 : whh1;
  const float* bv = (task == 0) ? bih0 : (task == 1) ? bhh0 : (task == 2) ? bih1 : bhh1;

  // ---- one-time weight staging ----
  if (task == 0) {
    // full 16-col slice, 3 gates: 6144 chunks (96 KB)
#pragma unroll
    for (int i = 0; i < 24; ++i) {
      int s2 = i * 256 + tid;
      int g = s2 >> 11, rem = s2 & 2047, ks = rem >> 6, l = rem & 63;
      const uint16_t* gp = Bw + (size_t)(g * 64 + slice) * 16384 +
                           (size_t)ks * 512 + l * 8;
      async_cp16(gp, blds + (size_t)s2 * 8);
    }
  } else {
    // r,z gates for 32 cols (tiles 2w, 2w+1 per gate): 8192 chunks (128 KB)
    // LDS layout: offset(g,ct,K) = ((g*2+ct)*32 + K)*512 + lane*8 u16
#pragma unroll
    for (int i = 0; i < 32; ++i) {
      int s2 = i * 256 + tid;
      int g = s2 >> 12, rem = s2 & 4095, ct = rem >> 11, ks = (rem >> 6) & 31, l = rem & 63;
      const uint16_t* gp = Bw + (size_t)(g * 64 + 2 * w + ct) * 16384 +
                           (size_t)ks * 512 + l * 8;
      async_cp16(gp, blds + (size_t)s2 * 8);
    }
  }
  drain_vmem();
  __syncthreads();

  if (task == 0) {
    // -------- task0: 16-col xlin0 producer --------
    const int c = slice * 16 + r15;
    const float br = bv[c], bz = bv[1024 + c], bn = bv[2048 + c];
    const int* ring = done1 + (slice >> 1) * 16;   // consumer WG of this slice
    for (int t = 0; t < SLEN; ++t) {
      if (wv == 0) pollA(ring, t - 7, flags, 0, flags, 0);
      __syncthreads();
      f32x4 acc0 = {0.f, 0.f, 0.f, 0.f}, acc1 = acc0, acc2 = acc0;
      bf16x8 av[16];
      const uint16_t* ap = x_bf + (size_t)t * HB + (size_t)(16 * wv + r15) * 1024 + q * 8;
#pragma unroll
      for (int ks = 0; ks < 16; ++ks) av[ks] = *(const bf16x8*)(ap + ks * 32);
      mfma16(av, blds, lane, acc0, acc1, acc2);
#pragma unroll
      for (int ks = 0; ks < 16; ++ks) av[ks] = *(const bf16x8*)(ap + 512 + ks * 32);
      mfma16(av, blds + 8192, lane, acc0, acc1, acc2);
      float* dst = xl0 + (size_t)(t & 7) * XLSLOT + (size_t)slice * 64 * 48;
#pragma unroll
      for (int rg = 0; rg < 4; ++rg) {
        int mm = m + rg;
        st_f32_llc(dst + (size_t)mm * 48 + r15,      acc0[rg] + br);
        st_f32_llc(dst + (size_t)mm * 48 + 16 + r15, acc1[rg] + bz);
        st_f32_llc(dst + (size_t)mm * 48 + 32 + r15, acc2[rg] + bn);
      }
      drain_vmem();
      __syncthreads();
      if (tid == 0) st_flag(done0 + slice * 16, t + 1);
    }
    return;
  }

  // -------- tasks 1,2,3: 32-col slice [32w, 32w+32) --------
  float bR[2], bZ[2], bN[2];
#pragma unroll
  for (int ct = 0; ct < 2; ++ct) {
    int c = w * 32 + ct * 16 + r15;
    bR[ct] = bv[c]; bZ[ct] = bv[1024 + c]; bN[ct] = bv[2048 + c];
  }

  // n-gate weight stream bases (tiles 128 + 2w, 129 + 2w)
  const bf16x8* wn0 = (const bf16x8*)(Bw + (size_t)(128 + 2 * w) * 16384);
  const bf16x8* wn1 = (const bf16x8*)(Bw + (size_t)(129 + 2 * w) * 16384);

  float hreg[4][2];
  if (task != 2) {
    const int layer = (task == 3);
#pragma unroll
    for (int rg = 0; rg < 4; ++rg)
#pragma unroll
      for (int ct = 0; ct < 2; ++ct)
        hreg[rg][ct] = hx[(size_t)layer * HB + (size_t)(m + rg) * 1024 + w * 32 + ct * 16 + r15];
  }

  for (int t = 0; t < SLEN; ++t) {
    // ---- combined pre-step wait ----
    if (wv == 0) {
      if (task == 1) {
        pollA(done0 + (2 * w + (lane & 1)) * 16, (lane < 2) ? t + 1 : 0,  // xlin0 slices
              done1 + (lane & 31) * 16, (lane < 32) ? t : 0,              // h0 step t-1 done (all)
              done2 + (lane & 31) * 16, (lane < 32) ? t - 3 : 0);         // h0 4-ring reuse safe
      } else if (task == 2) {
        pollA(done1 + (lane & 31) * 16, (lane < 32) ? t + 1 : 0,          // h0[t] complete (all)
              done3 + w * 16, t - 7,                                      // xl1 ring free (pairwise)
              flags, 0);
      } else {
        pollA(done2 + w * 16, t + 1,                                      // xlin1 slices ready (pairwise)
              done3 + (lane & 31) * 16, (lane < 32) ? t : 0,              // h1 ping-pong safe (all)
              flags, 0);
      }
    }
    __syncthreads();

    // ---- xv loads (GRU tasks): issued early, consumed at elementwise ----
    float xv[3][4][2];
    if (task != 2) {
      const float* xlr = (task == 1) ? xl0 : xl1;
      const float* slot = xlr + (size_t)(t & 7) * XLSLOT;
#pragma unroll
      for (int g = 0; g < 3; ++g)
#pragma unroll
        for (int rg = 0; rg < 4; ++rg)
#pragma unroll
          for (int ct = 0; ct < 2; ++ct)
            xv[g][rg][ct] = ld_f32_llc(slot + (size_t)((2 * w + ct) * 64 + m + rg) * 48 +
                                       g * 16 + r15);
    }

    // ---- n-gate prefetch prologue (L2 cached loads) ----
    bf16x8 nf[4][2];
#pragma unroll
    for (int p = 0; p < 4; ++p) {
      nf[p][0] = wn0[p * 64 + lane];
      nf[p][1] = wn1[p * 64 + lane];
    }

    // ---- A source ----
    const uint16_t* hring = (task == 3) ? h1b : h0b;
    int slot;
    if (task == 1) slot = t & 3;            // h0[t] lives in slot t&3
    else if (task == 2) slot = (t + 1) & 3; // out0[t] = h0 written at step t
    else slot = t & 1;                      // h1 ping-pong
    const uint16_t* ap = hring + (size_t)slot * HB + (size_t)(16 * wv + r15) * 1024 + q * 8;

    f32x4 aR[2], aZ[2], aN[2];
#pragma unroll
    for (int ct = 0; ct < 2; ++ct) { aR[ct] = {0,0,0,0}; aZ[ct] = {0,0,0,0}; aN[ct] = {0,0,0,0}; }

    bf16x8 av[16];
#pragma unroll
    for (int half = 0; half < 2; ++half) {
      load_a16_sc1(ap + half * 512, av);    // vmcnt(0) inside (covers prefetches too)
#pragma unroll
      for (int ks = 0; ks < 16; ++ks) {
        const int K = half * 16 + ks;
        const uint16_t* lb = blds + (size_t)K * 512 + (size_t)lane * 8;
        bf16x8 r0 = *(const bf16x8*)(lb);
        bf16x8 r1 = *(const bf16x8*)(lb + 16384);
        bf16x8 z0 = *(const bf16x8*)(lb + 32768);
        bf16x8 z1 = *(const bf16x8*)(lb + 49152);
        aR[0] = MFMA_BF16(av[ks], r0, aR[0], 0, 0, 0);
        aR[1] = MFMA_BF16(av[ks], r1, aR[1], 0, 0, 0);
        aZ[0] = MFMA_BF16(av[ks], z0, aZ[0], 0, 0, 0);
        aZ[1] = MFMA_BF16(av[ks], z1, aZ[1], 0, 0, 0);
        aN[0] = MFMA_BF16(av[ks], nf[K & 3][0], aN[0], 0, 0, 0);
        aN[1] = MFMA_BF16(av[ks], nf[K & 3][1], aN[1], 0, 0, 0);
        if (K < 28) {                       // prefetch K+4
          nf[K & 3][0] = wn0[(K + 4) * 64 + lane];
          nf[K & 3][1] = wn1[(K + 4) * 64 + lane];
        }
      }
    }

    if (task == 2) {
      float* dst = xl1 + (size_t)(t & 7) * XLSLOT;
#pragma unroll
      for (int rg = 0; rg < 4; ++rg)
#pragma unroll
        for (int ct = 0; ct < 2; ++ct) {
          float* p = dst + (size_t)((2 * w + ct) * 64 + m + rg) * 48 + r15;
          st_f32_llc(p,      aR[ct][rg] + bR[ct]);
          st_f32_llc(p + 16, aZ[ct][rg] + bZ[ct]);
          st_f32_llc(p + 32, aN[ct][rg] + bN[ct]);
        }
      drain_vmem();
      __syncthreads();
      if (tid == 0) st_flag(done2 + w * 16, t + 1);
    } else {
      uint16_t* hbw = ((task == 1) ? h0b : h1b) +
                      (size_t)((task == 1) ? ((t + 1) & 3) : ((t + 1) & 1)) * HB;
#pragma unroll
      for (int rg = 0; rg < 4; ++rg)
#pragma unroll
        for (int ct = 0; ct < 2; ++ct) {
          float r = sigmoid_fast(xv[0][rg][ct] + aR[ct][rg] + bR[ct]);
          float z = sigmoid_fast(xv[1][rg][ct] + aZ[ct][rg] + bZ[ct]);
          float n = tanh_fast(xv[2][rg][ct] + r * (aN[ct][rg] + bN[ct]));
          float h = (1.0f - z) * n + z * hreg[rg][ct];
          hreg[rg][ct] = h;
          st_u16_llc(hbw + (size_t)(m + rg) * 1024 + w * 32 + ct * 16 + r15, f32_to_bf16(h));
        }
      drain_vmem();
      __syncthreads();
      if (tid == 0) st_flag(((task == 1) ? done1 : done3) + w * 16, t + 1);
      if (task == 3) {
        // host-only out[] stores AFTER the flag (off the recurrence drain path)
#pragma unroll
        for (int rg = 0; rg < 4; ++rg)
#pragma unroll
          for (int ct = 0; ct < 2; ++ct)
            out[(size_t)t * HB + (size_t)(m + rg) * 1024 + w * 32 + ct * 16 + r15] = hreg[rg][ct];
      }
    }
  }

  // final hidden state (L,B,H) appended after out sequence
  if (task != 2) {
    const int layer = (task == 3);
#pragma unroll
    for (int rg = 0; rg < 4; ++rg)
#pragma unroll
      for (int ct = 0; ct < 2; ++ct)
        out[(size_t)SLEN * HB + (size_t)layer * HB + (size_t)(m + rg) * 1024 +
            w * 32 + ct * 16 + r15] = hreg[rg][ct];
  }
}

// ---- host -------------------------------------------------------------------

extern "C" void kernel_launch(void* const* d_in, const int* in_sizes, int n_in,
                              void* d_out, int out_size, void* d_ws, size_t ws_size,
                              hipStream_t stream) {
  (void)in_sizes; (void)n_in; (void)out_size; (void)ws_size;
  const float* x = (const float*)d_in[0];
  const float* hx = (const float*)d_in[1];
  const float* wih0f = (const float*)d_in[2];
  const float* whh0f = (const float*)d_in[3];
  const float* bih0 = (const float*)d_in[4];
  const float* bhh0 = (const float*)d_in[5];
  const float* wih1f = (const float*)d_in[6];
  const float* whh1f = (const float*)d_in[7];
  const float* bih1 = (const float*)d_in[8];
  const float* bhh1 = (const float*)d_in[9];
  float* out = (float*)d_out;

  char* ws = (char*)d_ws;
  uint16_t* x_bf = (uint16_t*)ws; ws += (size_t)SLEN * HB * 2;     // 64 MB
  uint16_t* wih0 = (uint16_t*)ws; ws += (size_t)G3 * 1024 * 2;     // 6 MB each
  uint16_t* whh0 = (uint16_t*)ws; ws += (size_t)G3 * 1024 * 2;
  uint16_t* wih1 = (uint16_t*)ws; ws += (size_t)G3 * 1024 * 2;
  uint16_t* whh1 = (uint16_t*)ws; ws += (size_t)G3 * 1024 * 2;
  float* xl0 = (float*)ws; ws += (size_t)8 * XLSLOT * 4;           // 6.3 MB ring (8 slots)
  float* xl1 = (float*)ws; ws += (size_t)8 * XLSLOT * 4;           // 6.3 MB ring
  uint16_t* h0b = (uint16_t*)ws; ws += (size_t)4 * HB * 2;         // 512 KB (4-ring)
  uint16_t* h1b = (uint16_t*)ws; ws += (size_t)2 * HB * 2;         // 256 KB (ping-pong)
  int* flags = (int*)ws; ws += 16384;                              // 4096 ints, 64B lines

  convert_x<<<16384, 256, 0, stream>>>(x, x_bf);
  pack_w<<<1536, 256, 0, stream>>>(wih0f, wih0);
  pack_w<<<1536, 256, 0, stream>>>(whh0f, whh0);
  pack_w<<<1536, 256, 0, stream>>>(wih1f, wih1);
  pack_w<<<1536, 256, 0, stream>>>(whh1f, whh1);
  init_state<<<256, 256, 0, stream>>>(hx, h0b, h1b, flags);

  const uint16_t* cx = x_bf;
  const uint16_t* cw0 = wih0; const uint16_t* cw1 = whh0;
  const uint16_t* cw2 = wih1; const uint16_t* cw3 = whh1;
  void* args[] = {(void*)&cx, (void*)&cw0, (void*)&cw1, (void*)&cw2, (void*)&cw3,
                  (void*)&bih0, (void*)&bhh0, (void*)&bih1, (void*)&bhh1, (void*)&hx,
                  (void*)&xl0, (void*)&xl1, (void*)&h0b, (void*)&h1b,
                  (void*)&flags, (void*)&out};
  hipError_t e = hipLaunchCooperativeKernel(reinterpret_cast<void*>(gru_persist),
                                            dim3(160), dim3(256), args, 0u, stream);
  if (e != hipSuccess) {
    gru_persist<<<dim3(160), dim3(256), 0, stream>>>(
        x_bf, wih0, whh0, wih1, whh1, bih0, bhh0, bih1, bhh1, hx,
        xl0, xl1, h0b, h1b, flags, out);
  }
}

// Round 7
// 4807.978 us; speedup vs baseline: 1.2200x; 1.2200x over previous
//
#include <hip/hip_runtime.h>
#include <stdint.h>

// GRU S=512, B=64, D=H=1024, L=2 — persistent cooperative pipeline, v8.
// Back to the proven v3 geometry (4 tasks x 64 slices x 16 cols, 256 WGs,
// LDS-resident weights, identical loaders). v8 attacks the sc1 STORE path:
//   * o0r duplicate eliminated — task2 reads h0b (ring deepened to 4).
//   * Wide device-scope stores via wave-local LDS transpose:
//       h:  1x global_store_dwordx2 sc1 per lane   (was 8x 2-byte h+o0r)
//       xl: 3x global_store_dwordx4 sc1 per lane   (was 12x 4-byte)
//     4-8x fewer LLC write transactions inside the recurrence-critical
//     drain. Read side and sync structure unchanged from v3.

#define SLEN 512
#define HB   65536
#define G3   3072
#define XLSLOT (64 * 64 * 48)   // floats per xlin ring slot: [slice][row64][gate3][col16]

typedef __attribute__((ext_vector_type(8))) short bf16x8;
typedef __attribute__((ext_vector_type(4))) float f32x4;
typedef __attribute__((ext_vector_type(8))) uint16_t u16x8;

__device__ __forceinline__ uint16_t f32_to_bf16(float f) {
  uint32_t u = __float_as_uint(f);
  uint32_t r = u + 0x7FFFu + ((u >> 16) & 1u);
  return (uint16_t)(r >> 16);
}
__device__ __forceinline__ float sigmoid_fast(float x) { return 1.0f / (1.0f + __expf(-x)); }
__device__ __forceinline__ float tanh_fast(float x) { return 1.0f - 2.0f / (1.0f + __expf(2.0f * x)); }
__device__ __forceinline__ void async_cp16(const void* g, void* l) {
  __builtin_amdgcn_global_load_lds((const __attribute__((address_space(1))) void*)g,
                                   (__attribute__((address_space(3))) void*)l, 16, 0, 0);
}
__device__ __forceinline__ void st_f32_llc(float* p, float v) {
  __hip_atomic_store(p, v, __ATOMIC_RELAXED, __HIP_MEMORY_SCOPE_AGENT);
}
__device__ __forceinline__ void st_b64_sc1(void* p, uint2 v) {
  asm volatile("global_store_dwordx2 %0, %1, off sc1" :: "v"(p), "v"(v) : "memory");
}
__device__ __forceinline__ void st_b128_sc1(void* p, f32x4 v) {
  asm volatile("global_store_dwordx4 %0, %1, off sc1" :: "v"(p), "v"(v) : "memory");
}
__device__ __forceinline__ void drain_vmem() {
  asm volatile("s_waitcnt vmcnt(0)" ::: "memory");
}
__device__ __forceinline__ int ld_flag(const int* p) {
  return __hip_atomic_load(p, __ATOMIC_RELAXED, __HIP_MEMORY_SCOPE_AGENT);
}
__device__ __forceinline__ void st_flag(int* p, int v) {
  __hip_atomic_store(p, v, __ATOMIC_RELAXED, __HIP_MEMORY_SCOPE_AGENT);
}

// ---- prep kernels -----------------------------------------------------------

__global__ __launch_bounds__(256) void convert_x(const float* __restrict__ src,
                                                 uint16_t* __restrict__ dst) {
  size_t i = ((size_t)blockIdx.x * 256 + threadIdx.x) * 8;
  const float4* s = (const float4*)(src + i);
  float4 a = s[0], b = s[1];
  u16x8 v;
  v[0] = f32_to_bf16(a.x); v[1] = f32_to_bf16(a.y);
  v[2] = f32_to_bf16(a.z); v[3] = f32_to_bf16(a.w);
  v[4] = f32_to_bf16(b.x); v[5] = f32_to_bf16(b.y);
  v[6] = f32_to_bf16(b.z); v[7] = f32_to_bf16(b.w);
  *(u16x8*)(dst + i) = v;
}

// (3072x1024 f32, row-major) -> MFMA B-fragment order:
// chunk = (tile*32 + ks)*64 + lane, holding w[16*tile + (lane&15)][32ks + (lane>>4)*8 ..+7]
__global__ __launch_bounds__(256) void pack_w(const float* __restrict__ src,
                                              uint16_t* __restrict__ dst) {
  int tid = blockIdx.x * 256 + threadIdx.x;
  int tile = tid >> 11, rem = tid & 2047, ks = rem >> 6, lane = rem & 63;
  int row = tile * 16 + (lane & 15);
  int k0 = ks * 32 + (lane >> 4) * 8;
  const float* s = src + (size_t)row * 1024 + k0;
  u16x8 v;
#pragma unroll
  for (int j = 0; j < 8; ++j) v[j] = f32_to_bf16(s[j]);
  *(u16x8*)(dst + (size_t)tid * 8) = v;
}

__global__ __launch_bounds__(256) void init_state(const float* __restrict__ hx,
                                                  uint16_t* __restrict__ h0b,
                                                  uint16_t* __restrict__ h1b,
                                                  int* __restrict__ flags) {
  int i = blockIdx.x * 256 + threadIdx.x;   // 65536 threads
  h0b[i] = f32_to_bf16(hx[i]);              // h0 ring slot 0
  h1b[i] = f32_to_bf16(hx[HB + i]);         // h1 ring slot 0
  if (blockIdx.x < 16) flags[blockIdx.x * 256 + threadIdx.x] = 0;  // 4096 ints
}

// ---- parallel flag wait (wave 0 only) --------------------------------------
// Up to 3 per-lane conditions: *aK >= tK, disabled if tK <= 0. Monotonic.
__device__ __forceinline__ void pollA(const int* a0, int t0,
                                      const int* a1, int t1,
                                      const int* a2, int t2) {
  const int BIG = 0x7fffffff;
  int v0 = (t0 > 0) ? ld_flag(a0) : BIG;
  int v1 = (t1 > 0) ? ld_flag(a1) : BIG;
  int v2 = (t2 > 0) ? ld_flag(a2) : BIG;
  int it = 0;
  while (!__all((v0 >= t0) & (v1 >= t1) & (v2 >= t2))) {
    __builtin_amdgcn_s_sleep(1);
    if (v0 < t0) v0 = ld_flag(a0);
    if (v1 < t1) v1 = ld_flag(a1);
    if (v2 < t2) v2 = ld_flag(a2);
    if (++it > (1 << 22)) break;   // safety valve vs hang
  }
}

// ---- device-scope (sc1) load batches ---------------------------------------

// 16 A-fragments, waits vmcnt(0) inside.
__device__ __forceinline__ void load_a16_sc1(const uint16_t* p, bf16x8* a) {
  asm volatile(
      "global_load_dwordx4 %0, %16, off sc1\n\t"
      "global_load_dwordx4 %1, %16, off offset:64 sc1\n\t"
      "global_load_dwordx4 %2, %16, off offset:128 sc1\n\t"
      "global_load_dwordx4 %3, %16, off offset:192 sc1\n\t"
      "global_load_dwordx4 %4, %16, off offset:256 sc1\n\t"
      "global_load_dwordx4 %5, %16, off offset:320 sc1\n\t"
      "global_load_dwordx4 %6, %16, off offset:384 sc1\n\t"
      "global_load_dwordx4 %7, %16, off offset:448 sc1\n\t"
      "global_load_dwordx4 %8, %16, off offset:512 sc1\n\t"
      "global_load_dwordx4 %9, %16, off offset:576 sc1\n\t"
      "global_load_dwordx4 %10, %16, off offset:640 sc1\n\t"
      "global_load_dwordx4 %11, %16, off offset:704 sc1\n\t"
      "global_load_dwordx4 %12, %16, off offset:768 sc1\n\t"
      "global_load_dwordx4 %13, %16, off offset:832 sc1\n\t"
      "global_load_dwordx4 %14, %16, off offset:896 sc1\n\t"
      "global_load_dwordx4 %15, %16, off offset:960 sc1\n\t"
      "s_waitcnt vmcnt(0)"
      : "=&v"(a[0]), "=&v"(a[1]), "=&v"(a[2]), "=&v"(a[3]),
        "=&v"(a[4]), "=&v"(a[5]), "=&v"(a[6]), "=&v"(a[7]),
        "=&v"(a[8]), "=&v"(a[9]), "=&v"(a[10]), "=&v"(a[11]),
        "=&v"(a[12]), "=&v"(a[13]), "=&v"(a[14]), "=&v"(a[15])
      : "v"(p)
      : "memory");
}

// 16 A-fragments + 12 xlin floats (offsets rg*192 + g*64), one vmcnt(0).
__device__ __forceinline__ void load_a16_xl12_sc1(const uint16_t* p, const float* px,
                                                  bf16x8* a, float* x) {
  asm volatile(
      "global_load_dword %16, %29, off sc1\n\t"
      "global_load_dword %17, %29, off offset:64 sc1\n\t"
      "global_load_dword %18, %29, off offset:128 sc1\n\t"
      "global_load_dword %19, %29, off offset:192 sc1\n\t"
      "global_load_dword %20, %29, off offset:256 sc1\n\t"
      "global_load_dword %21, %29, off offset:320 sc1\n\t"
      "global_load_dword %22, %29, off offset:384 sc1\n\t"
      "global_load_dword %23, %29, off offset:448 sc1\n\t"
      "global_load_dword %24, %29, off offset:512 sc1\n\t"
      "global_load_dword %25, %29, off offset:576 sc1\n\t"
      "global_load_dword %26, %29, off offset:640 sc1\n\t"
      "global_load_dword %27, %29, off offset:704 sc1\n\t"
      "global_load_dwordx4 %0, %28, off sc1\n\t"
      "global_load_dwordx4 %1, %28, off offset:64 sc1\n\t"
      "global_load_dwordx4 %2, %28, off offset:128 sc1\n\t"
      "global_load_dwordx4 %3, %28, off offset:192 sc1\n\t"
      "global_load_dwordx4 %4, %28, off offset:256 sc1\n\t"
      "global_load_dwordx4 %5, %28, off offset:320 sc1\n\t"
      "global_load_dwordx4 %6, %28, off offset:384 sc1\n\t"
      "global_load_dwordx4 %7, %28, off offset:448 sc1\n\t"
      "global_load_dwordx4 %8, %28, off offset:512 sc1\n\t"
      "global_load_dwordx4 %9, %28, off offset:576 sc1\n\t"
      "global_load_dwordx4 %10, %28, off offset:640 sc1\n\t"
      "global_load_dwordx4 %11, %28, off offset:704 sc1\n\t"
      "global_load_dwordx4 %12, %28, off offset:768 sc1\n\t"
      "global_load_dwordx4 %13, %28, off offset:832 sc1\n\t"
      "global_load_dwordx4 %14, %28, off offset:896 sc1\n\t"
      "global_load_dwordx4 %15, %28, off offset:960 sc1\n\t"
      "s_waitcnt vmcnt(0)"
      : "=&v"(a[0]), "=&v"(a[1]), "=&v"(a[2]), "=&v"(a[3]),
        "=&v"(a[4]), "=&v"(a[5]), "=&v"(a[6]), "=&v"(a[7]),
        "=&v"(a[8]), "=&v"(a[9]), "=&v"(a[10]), "=&v"(a[11]),
        "=&v"(a[12]), "=&v"(a[13]), "=&v"(a[14]), "=&v"(a[15]),
        "=&v"(x[0]), "=&v"(x[1]), "=&v"(x[2]), "=&v"(x[3]),
        "=&v"(x[4]), "=&v"(x[5]), "=&v"(x[6]), "=&v"(x[7]),
        "=&v"(x[8]), "=&v"(x[9]), "=&v"(x[10]), "=&v"(x[11])
      : "v"(p), "v"(px)
      : "memory");
}

// ---- persistent kernel ------------------------------------------------------

#define MFMA_BF16 __builtin_amdgcn_mfma_f32_16x16x32_bf16

// B fragments for 16 K-chunks starting at bbase; gate stride 16384 u16 (32 KB).
__device__ __forceinline__ void mfma16(const bf16x8* av, const uint16_t* bbase, int lane,
                                       f32x4& acc0, f32x4& acc1, f32x4& acc2) {
#pragma unroll
  for (int ks = 0; ks < 16; ++ks) {
    const uint16_t* bp = bbase + (size_t)(ks * 64 + lane) * 8;
    bf16x8 b0 = *(const bf16x8*)(bp);
    bf16x8 b1 = *(const bf16x8*)(bp + 16384);
    bf16x8 b2 = *(const bf16x8*)(bp + 32768);
    acc0 = MFMA_BF16(av[ks], b0, acc0, 0, 0, 0);
    acc1 = MFMA_BF16(av[ks], b1, acc1, 0, 0, 0);
    acc2 = MFMA_BF16(av[ks], b2, acc2, 0, 0, 0);
  }
}

__global__ __launch_bounds__(256, 1) void gru_persist(
    const uint16_t* __restrict__ x_bf,
    const uint16_t* __restrict__ wih0, const uint16_t* __restrict__ whh0,
    const uint16_t* __restrict__ wih1, const uint16_t* __restrict__ whh1,
    const float* __restrict__ bih0, const float* __restrict__ bhh0,
    const float* __restrict__ bih1, const float* __restrict__ bhh1,
    const float* __restrict__ hx,
    float* __restrict__ xl0, float* __restrict__ xl1,
    uint16_t* __restrict__ h0b, uint16_t* __restrict__ h1b,
    int* __restrict__ flags,
    float* __restrict__ out) {
  // 96 KB weights + 12 KB store-transpose stage (union across tasks) = 108 KB.
  __shared__ uint16_t blds[49152];
  __shared__ float xstage[4][16][48];       // task0/2 xl stage; tasks1/3 reuse as u16 h stage

  const int task = blockIdx.x >> 6;
  const int slice = blockIdx.x & 63;
  const int tid = threadIdx.x;
  const int lane = tid & 63;
  const int wv = tid >> 6;
  const int r15 = lane & 15;
  const int q = lane >> 4;
  const int c = slice * 16 + r15;           // output column
  const int m = 16 * wv + 4 * q;            // batch row base

  // single-int store-only flags, one 64B line per slice: doneT[slice*16]
  int* done0 = flags;
  int* done1 = flags + 1024;
  int* done2 = flags + 2048;
  int* done3 = flags + 3072;
  int* mydone = (task == 0) ? done0 : (task == 1) ? done1 : (task == 2) ? done2 : done3;

  const uint16_t* Bw = (task == 0) ? wih0 : (task == 1) ? whh0 : (task == 2) ? wih1 : whh1;
  const float* bv = (task == 0) ? bih0 : (task == 1) ? bhh0 : (task == 2) ? bih1 : bhh1;
  const float br = bv[c], bz = bv[1024 + c], bn = bv[2048 + c];

  float hreg[4];
  if (task == 1 || task == 3) {
    const int layer = (task == 3);
#pragma unroll
    for (int rg = 0; rg < 4; ++rg)
      hreg[rg] = hx[(size_t)layer * HB + (size_t)(m + rg) * 1024 + c];
  }

  // ---- one-time weight stage: 6144 chunks of 16B -> blds (wave-linear dest)
#pragma unroll
  for (int i = 0; i < 24; ++i) {
    int s2 = i * 256 + tid;                 // (g, ks, l)
    int g = s2 >> 11, rem = s2 & 2047, ks = rem >> 6, l = rem & 63;
    const uint16_t* gp = Bw + (size_t)(g * 64 + slice) * 16384 +
                         (size_t)ks * 512 + l * 8;
    async_cp16(gp, blds + (size_t)s2 * 8);
  }
  drain_vmem();
  __syncthreads();                          // all waves' chunks resident

  // wide-store readback indices (per lane): row within wave tile + col quarter
  const int sr = lane >> 2;                 // 0..15
  const int sc = lane & 3;                  // 0..3

  for (int t = 0; t < SLEN; ++t) {
    // ---- single combined wait per step (wave 0 polls, others park) ----
    if (wv == 0) {
      if (task == 0) {
        pollA(done1 + slice * 16, t - 7,     // xl0 ring slot free (pairwise)
              flags, 0, flags, 0);
      } else if (task == 1) {
        pollA(done0 + slice * 16, t + 1,     // xlin0[t] slice ready (pairwise)
              done1 + lane * 16, t,          // h0[t] data complete (all 64)
              done2 + lane * 16, t - 3);     // h0 4-ring reuse safe (all 64)
      } else if (task == 2) {
        pollA(done1 + lane * 16, t + 1,      // h0[t+1] = out0[t] complete (all)
              done3 + slice * 16, t - 7,     // xl1 ring slot free (pairwise)
              flags, 0);
      } else {
        pollA(done2 + slice * 16, t + 1,     // xlin1[t] slice ready (pairwise)
              done3 + lane * 16, t,          // h1[t] + ping-pong safe (all)
              flags, 0);
      }
    }
    __syncthreads();

    f32x4 acc0 = {0.f, 0.f, 0.f, 0.f}, acc1 = acc0, acc2 = acc0;
    bf16x8 av[16];
    float xv[12];

    if (task == 1 || task == 3) {
      const float* xlr = (task == 1) ? xl0 : xl1;
      const int rslot = (task == 1) ? (t & 3) : (t & 1);
      const uint16_t* ap = ((task == 1) ? h0b : h1b) + (size_t)rslot * HB +
                           (size_t)(16 * wv + r15) * 1024 + q * 8;
      const float* xlp = xlr + (size_t)(t & 7) * XLSLOT + (size_t)(slice * 64 + m) * 48 + r15;

      load_a16_xl12_sc1(ap, xlp, av, xv);   // h half 0 + xlin, vmcnt(0) inside
      mfma16(av, blds, lane, acc0, acc1, acc2);
      load_a16_sc1(ap + 512, av);           // h half 1
      mfma16(av, blds + 8192, lane, acc0, acc1, acc2);

      const int wslot = (task == 1) ? ((t + 1) & 3) : ((t + 1) & 1);
      uint16_t* hbw = ((task == 1) ? h0b : h1b) + (size_t)wslot * HB;
      uint16_t* hstage = (uint16_t*)&xstage[wv][0][0];   // 16x16 u16 wave tile
#pragma unroll
      for (int rg = 0; rg < 4; ++rg) {
        float r = sigmoid_fast(xv[rg * 3 + 0] + acc0[rg] + br);
        float z = sigmoid_fast(xv[rg * 3 + 1] + acc1[rg] + bz);
        float n = tanh_fast(xv[rg * 3 + 2] + r * (acc2[rg] + bn));
        float h = (1.0f - z) * n + z * hreg[rg];
        hreg[rg] = h;
        hstage[(4 * q + rg) * 16 + r15] = f32_to_bf16(h);  // wave-local stage
      }
      // readback (same wave) and ONE wide sc1 store per lane
      uint2 v2 = *(const uint2*)&hstage[sr * 16 + sc * 4];
      st_b64_sc1(hbw + (size_t)(16 * wv + sr) * 1024 + slice * 16 + sc * 4, v2);
      drain_vmem();                         // this wave's store at LLC
      __syncthreads();                      // => ALL waves' stores at LLC
      if (tid == 0) st_flag(mydone + slice * 16, t + 1);
      if (task == 3) {
        // host-only out[] stores AFTER the flag (off the recurrence drain path)
#pragma unroll
        for (int rg = 0; rg < 4; ++rg)
          out[(size_t)t * HB + (size_t)(m + rg) * 1024 + c] = hreg[rg];
      }
    } else {
      if (task == 0) {
        const uint16_t* ap = x_bf + (size_t)t * HB + (size_t)(16 * wv + r15) * 1024 + q * 8;
#pragma unroll
        for (int ks = 0; ks < 16; ++ks) av[ks] = *(const bf16x8*)(ap + ks * 32);
        mfma16(av, blds, lane, acc0, acc1, acc2);
#pragma unroll
        for (int ks = 0; ks < 16; ++ks) av[ks] = *(const bf16x8*)(ap + 512 + ks * 32);
        mfma16(av, blds + 8192, lane, acc0, acc1, acc2);
      } else {
        // task2 reads out0[t] = h0[t+1] directly from the h0 ring (slot (t+1)&3)
        const uint16_t* ap = h0b + (size_t)((t + 1) & 3) * HB +
                             (size_t)(16 * wv + r15) * 1024 + q * 8;
        load_a16_sc1(ap, av);
        mfma16(av, blds, lane, acc0, acc1, acc2);
        load_a16_sc1(ap + 512, av);
        mfma16(av, blds + 8192, lane, acc0, acc1, acc2);
      }
      // stage 12 results/lane in LDS, emit 3 wide sc1 stores per lane
#pragma unroll
      for (int rg = 0; rg < 4; ++rg) {
        xstage[wv][4 * q + rg][r15]      = acc0[rg] + br;
        xstage[wv][4 * q + rg][16 + r15] = acc1[rg] + bz;
        xstage[wv][4 * q + rg][32 + r15] = acc2[rg] + bn;
      }
      float* dst = ((task == 0) ? xl0 : xl1) + (size_t)(t & 7) * XLSLOT +
                   (size_t)slice * 64 * 48 + (size_t)(16 * wv + sr) * 48 + sc * 12;
      const float* srcp = &xstage[wv][sr][sc * 12];
      st_b128_sc1(dst,     *(const f32x4*)(srcp));
      st_b128_sc1(dst + 4, *(const f32x4*)(srcp + 4));
      st_b128_sc1(dst + 8, *(const f32x4*)(srcp + 8));
      drain_vmem();
      __syncthreads();
      if (tid == 0) st_flag(mydone + slice * 16, t + 1);
    }
  }

  // final hidden state (L,B,H) appended after out sequence
  if (task == 1 || task == 3) {
    const int layer = (task == 3);
#pragma unroll
    for (int rg = 0; rg < 4; ++rg)
      out[(size_t)SLEN * HB + (size_t)layer * HB + (size_t)(m + rg) * 1024 + c] = hreg[rg];
  }
}

// ---- host -------------------------------------------------------------------

extern "C" void kernel_launch(void* const* d_in, const int* in_sizes, int n_in,
                              void* d_out, int out_size, void* d_ws, size_t ws_size,
                              hipStream_t stream) {
  (void)in_sizes; (void)n_in; (void)out_size; (void)ws_size;
  const float* x = (const float*)d_in[0];
  const float* hx = (const float*)d_in[1];
  const float* wih0f = (const float*)d_in[2];
  const float* whh0f = (const float*)d_in[3];
  const float* bih0 = (const float*)d_in[4];
  const float* bhh0 = (const float*)d_in[5];
  const float* wih1f = (const float*)d_in[6];
  const float* whh1f = (const float*)d_in[7];
  const float* bih1 = (const float*)d_in[8];
  const float* bhh1 = (const float*)d_in[9];
  float* out = (float*)d_out;

  char* ws = (char*)d_ws;
  uint16_t* x_bf = (uint16_t*)ws; ws += (size_t)SLEN * HB * 2;     // 64 MB
  uint16_t* wih0 = (uint16_t*)ws; ws += (size_t)G3 * 1024 * 2;     // 6 MB each
  uint16_t* whh0 = (uint16_t*)ws; ws += (size_t)G3 * 1024 * 2;
  uint16_t* wih1 = (uint16_t*)ws; ws += (size_t)G3 * 1024 * 2;
  uint16_t* whh1 = (uint16_t*)ws; ws += (size_t)G3 * 1024 * 2;
  float* xl0 = (float*)ws; ws += (size_t)8 * XLSLOT * 4;           // 6.3 MB ring (8 slots)
  float* xl1 = (float*)ws; ws += (size_t)8 * XLSLOT * 4;           // 6.3 MB ring
  uint16_t* h0b = (uint16_t*)ws; ws += (size_t)4 * HB * 2;         // 512 KB (4-ring)
  uint16_t* h1b = (uint16_t*)ws; ws += (size_t)2 * HB * 2;         // 256 KB (ping-pong)
  int* flags = (int*)ws; ws += 16384;                              // 4096 ints, 64B lines

  convert_x<<<16384, 256, 0, stream>>>(x, x_bf);
  pack_w<<<1536, 256, 0, stream>>>(wih0f, wih0);
  pack_w<<<1536, 256, 0, stream>>>(whh0f, whh0);
  pack_w<<<1536, 256, 0, stream>>>(wih1f, wih1);
  pack_w<<<1536, 256, 0, stream>>>(whh1f, whh1);
  init_state<<<256, 256, 0, stream>>>(hx, h0b, h1b, flags);

  const uint16_t* cx = x_bf;
  const uint16_t* cw0 = wih0; const uint16_t* cw1 = whh0;
  const uint16_t* cw2 = wih1; const uint16_t* cw3 = whh1;
  void* args[] = {(void*)&cx, (void*)&cw0, (void*)&cw1, (void*)&cw2, (void*)&cw3,
                  (void*)&bih0, (void*)&bhh0, (void*)&bih1, (void*)&bhh1, (void*)&hx,
                  (void*)&xl0, (void*)&xl1, (void*)&h0b, (void*)&h1b,
                  (void*)&flags, (void*)&out};
  hipError_t e = hipLaunchCooperativeKernel(reinterpret_cast<void*>(gru_persist),
                                            dim3(256), dim3(256), args, 0u, stream);
  if (e != hipSuccess) {
    gru_persist<<<dim3(256), dim3(256), 0, stream>>>(
        x_bf, wih0, whh0, wih1, whh1, bih0, bhh0, bih1, bhh1, hx,
        xl0, xl1, h0b, h1b, flags, out);
  }
}